// Round 6
// baseline (213.903 us; speedup 1.0000x reference)
//
#include <hip/hip_runtime.h>
#include <hip/hip_bf16.h>

#define D 128
#define K 64
#define MROW 136   // padded LDS row stride (shorts): breaks power-of-2 bank strides

typedef __attribute__((ext_vector_type(8))) short short8;   // 8 bf16 in 4 VGPRs
typedef __attribute__((ext_vector_type(4))) float f32x4;
typedef __attribute__((ext_vector_type(2))) unsigned uint2v;

// round-to-nearest-even float -> bf16 bits (prep only)
__device__ inline short f2bf(float f) {
  union { float f; unsigned u; } v; v.f = f;
  unsigned u = v.u;
  return (short)((u + 0x7fffu + ((u >> 16) & 1u)) >> 16);
}

// packed f32x2 -> bf16x2 (v_cvt_pk_bf16_f32)
__device__ inline unsigned pk2(float a, float b) {
  union { __hip_bfloat162 h; unsigned u; } c;
  c.h = __float22bfloat162_rn(make_float2(a, b));
  return c.u;
}

// VALU-pipe 16-lane reduction (DPP row_ror) — keeps reductions off the LDS pipe
template<int CTRL>
__device__ inline float dpp_add(float v) {
  int r = __builtin_amdgcn_update_dpp(0, __float_as_int(v), CTRL, 0xf, 0xf, true);
  return v + __int_as_float(r);
}
__device__ inline float row16_allsum(float v) {
  v = dpp_add<0x121>(v);
  v = dpp_add<0x122>(v);
  v = dpp_add<0x124>(v);
  v = dpp_add<0x128>(v);
  return v;
}

// ws layout (floats): [0..16) accumulator; [16..80) mnorm[64]; [128..) bf16(2*m) as 8192 shorts
__global__ void prep_kernel(const float* __restrict__ m, float* ws) {
  const int j = blockIdx.x;     // 64 blocks x 64 threads
  const int t = threadIdx.x;
  float a0 = m[j * D + t * 2];
  float a1 = m[j * D + t * 2 + 1];
  short* mb = (short*)(ws + 128);
  mb[j * D + t * 2]     = f2bf(2.0f * a0);
  mb[j * D + t * 2 + 1] = f2bf(2.0f * a1);
  float s = a0 * a0 + a1 * a1;
  for (int off = 1; off < 64; off <<= 1) s += __shfl_xor(s, off, 64);
  if (t == 0) ws[16 + j] = s;
  if (j == 0 && t < 16) ws[t] = 0.0f;
}

// Copy-bench-shaped global loads (lane-linear float4, 2-tile VGPR ring),
// A-fragment layout recovered via per-wave-PRIVATE LDS exchange (lgkmcnt only,
// no barrier in the loop). B-frags from padded shared LDS (r3: conflicts ~0).
__launch_bounds__(256)
__global__ void main_kernel(const float* __restrict__ x, float* ws) {
  __shared__ short msB[64 * MROW];        // shared bf16(2*m), padded
  __shared__ short msA[4][16 * MROW];     // per-wave private A exchange tiles
  const float* mnorm = ws + 16;
  const short* mb = (const short*)(ws + 128);
  const int tid  = threadIdx.x;
  const int lane = tid & 63;
  const int wv   = tid >> 6;
  const int lid  = lane & 15;   // A row / C-D col (j)
  const int quad = lane >> 4;   // A k-group; C/D row = quad*4+reg

  const int wave = blockIdx.x * 4 + wv;   // 4096 waves
  const int base = wave * 4;              // 4 contiguous 16-row tiles per wave

  // Issue tiles 0 and 1 immediately: lane-linear, dense 16 lines/instr
  f32x4 v0[8], v1[8];
  {
    const f32x4* t0 = (const f32x4*)(x + (size_t)base * 2048);
    const f32x4* t1 = t0 + 512;
#pragma unroll
    for (int j = 0; j < 8; ++j) v0[j] = t0[j * 64 + lane];
#pragma unroll
    for (int j = 0; j < 8; ++j) v1[j] = t1[j * 64 + lane];
  }

  // Stage B once (all 256 threads), padded rows
#pragma unroll
  for (int i = 0; i < 4; ++i) {
    int g = i * 2048 + tid * 8;           // short index in 64x128
    int row = g >> 7, col = g & 127;
    *(short8*)(msB + row * MROW + col) = *(const short8*)(mb + g);
  }
  float mn[4];
#pragma unroll
  for (int jt = 0; jt < 4; ++jt) mn[jt] = mnorm[jt * 16 + lid];
  __syncthreads();   // the only block-wide barrier before the end

  short* As = msA[wv];
  // lane-linear -> row layout for the exchange write: floats f = j*256+lane*4
  const int wrow_hi = lane >> 5;          // +j*2
  const int wcol = (lane * 4) & 127;

  float hacc = 0.f;

#pragma unroll
  for (int it = 0; it < 4; ++it) {
    f32x4* cur = (it & 1) ? v1 : v0;

    // Convert current tile -> per-wave LDS (row layout, padded)
#pragma unroll
    for (int j = 0; j < 8; ++j) {
      f32x4 w = cur[j];
      uint2v p;
      p[0] = pk2(w[0], w[1]);
      p[1] = pk2(w[2], w[3]);
      *(uint2v*)(As + (j * 2 + wrow_hi) * MROW + wcol) = p;
    }

    // Refill the freed ring slot with tile it+2 (compile-time guard)
    if (it + 2 < 4) {
      const f32x4* tn = (const f32x4*)(x + (size_t)(base + it + 2) * 2048);
#pragma unroll
      for (int j = 0; j < 8; ++j) cur[j] = tn[j * 64 + lane];
    }

    // A-fragments from the wave's own LDS tile (lgkmcnt-only dependency)
    short8 a[4];
#pragma unroll
    for (int kk = 0; kk < 4; ++kk)
      a[kk] = *(const short8*)(As + lid * MROW + kk * 32 + quad * 8);

    f32x4 acc[4];
#pragma unroll
    for (int jt = 0; jt < 4; ++jt) acc[jt] = (f32x4){0.f, 0.f, 0.f, 0.f};
#pragma unroll
    for (int kk = 0; kk < 4; ++kk) {
#pragma unroll
      for (int jt = 0; jt < 4; ++jt) {
        short8 b = *(const short8*)(msB + (jt * 16 + lid) * MROW + kk * 32 + quad * 8);
        acc[jt] = __builtin_amdgcn_mfma_f32_16x16x32_bf16(a[kk], b, acc[jt], 0, 0, 0);
      }
    }

    // s = 2x.m - ||m||^2, |s| < ~30 -> no max pass. H = ln S0 - S1/S0.
#pragma unroll
    for (int r = 0; r < 4; ++r) {
      float s0 = acc[0][r] - mn[0];
      float s1 = acc[1][r] - mn[1];
      float s2 = acc[2][r] - mn[2];
      float s3 = acc[3][r] - mn[3];
      float e0 = __expf(s0), e1 = __expf(s1), e2 = __expf(s2), e3 = __expf(s3);
      float S0 = (e0 + e1) + (e2 + e3);
      float S1 = fmaf(s0, e0, fmaf(s1, e1, fmaf(s2, e2, s3 * e3)));
      S0 = row16_allsum(S0);
      S1 = row16_allsum(S1);
      float H = __logf(S0) - S1 / S0;
      if (lid == 0) hacc += H;   // lane owns row quad*4+r
    }
  }

  // wave reduce -> block reduce -> one atomic per block
  for (int off = 1; off < 64; off <<= 1) hacc += __shfl_xor(hacc, off, 64);
  __shared__ float red[4];
  if (lane == 0) red[wv] = hacc;
  __syncthreads();
  if (tid == 0) atomicAdd(ws, red[0] + red[1] + red[2] + red[3]);
}

__global__ void final_kernel(const float* __restrict__ m, const float* ws, float* out, int nRows) {
  __shared__ float mu[D];
  int lane = threadIdx.x;  // 64 threads
  for (int d = lane; d < D; d += 64) {
    float s = 0.f;
    for (int j = 0; j < K; ++j) s += m[j * D + d];
    mu[d] = s * (1.0f / K);
  }
  __syncthreads();
  const float* mr = m + lane * D;
  float dot = 0.f;
  for (int d = 0; d < D; ++d) dot += mu[d] * mr[d];
  float s = 2.f * dot - ws[16 + lane];  // shift-invariant: drop ||mu||^2
  float t = s - 20.f;                   // safe shift
  float e = __expf(t);
  float S0 = e, S1 = t * e;
  for (int off = 1; off < 64; off <<= 1) {
    S0 += __shfl_xor(S0, off, 64);
    S1 += __shfl_xor(S1, off, 64);
  }
  float inter = __logf(S0) - S1 / S0;
  if (lane == 0) {
    float intra = ws[0] / (float)nRows;
    out[0] = intra - inter;  // LAMB = 1
    out[1] = intra;
    out[2] = inter;
  }
}

extern "C" void kernel_launch(void* const* d_in, const int* in_sizes, int n_in,
                              void* d_out, int out_size, void* d_ws, size_t ws_size,
                              hipStream_t stream) {
  const float* x = (const float*)d_in[0];
  const float* m = (const float*)d_in[1];
  float* ws = (float*)d_ws;
  float* out = (float*)d_out;
  const int N = in_sizes[0] / D;        // 262144

  prep_kernel<<<64, 64, 0, stream>>>(m, ws);

  // 1024 blocks = 4096 waves x 4 tiles; ~35 KB LDS/block -> 4 blocks/CU,
  // target 16 waves/CU with VGPR ~120 (no min-waves bound: r3 spill lesson)
  main_kernel<<<1024, 256, 0, stream>>>(x, ws);

  final_kernel<<<1, 64, 0, stream>>>(m, ws, out, N);
}